// Round 6
// baseline (3327.753 us; speedup 1.0000x reference)
//
#include <hip/hip_runtime.h>

#define NT 1024
#define TSEQ 512

typedef float float2v __attribute__((ext_vector_type(2)));

__device__ __forceinline__ float sigmoid_(float x) { return 1.0f / (1.0f + __expf(-x)); }
__device__ __forceinline__ float tanh_(float x) { return 1.0f - 2.0f / (1.0f + __expf(2.0f * x)); }

// LDS-visibility-only barrier (validated rounds 2-5): drains lgkmcnt (ds ops)
// but NOT vmcnt, so global prefetch loads / h-stores stay in flight.
__device__ __forceinline__ void wg_barrier() {
    asm volatile("s_waitcnt lgkmcnt(0)" ::: "memory");
    __builtin_amdgcn_s_barrier();
}

// ---------------- prep kernel ----------------
// wbuf float4 index: (l*20 + g*5 + q)*1024 + tid -> W[g*100+rg][20f+4q .. +3]
// Padded K=200 row images with CLEAN x/h chunk split (20-k chunks):
//   layer0   : [x(5) 0(15) | h(100) @k20..119 | 0(80)]  -> f=0 x, f in[1,6) h, f>=6 zero
//   layers>=1: [x(100) | h(100)]                         -> f in[0,5) x, f in[5,10) h
extern "C" __global__ void prep_weights(const float* __restrict__ Wih0,
                                        const float* __restrict__ Whh0,
                                        const float* __restrict__ WihL,
                                        const float* __restrict__ WhhL,
                                        float4* __restrict__ wbuf) {
    int gid = blockIdx.x * 256 + threadIdx.x;  // 5*20*1024 = 102400 total
    if (gid >= 102400) return;
    int tid = gid & 1023;
    int lgq = gid >> 10;
    int gq = lgq % 20;          // g*5 + q
    int l = lgq / 20;
    int g = gq / 5, q = gq % 5;
    float tmp[4] = {0.f, 0.f, 0.f, 0.f};
    if (tid < 1000) {
        int f = tid / 100, rg = tid % 100;
        int row = g * 100 + rg;
        int k0 = 20 * f + 4 * q;
        for (int c = 0; c < 4; ++c) {
            int k = k0 + c;
            float w = 0.f;
            if (l == 0) {
                if (k < 5) w = Wih0[row * 5 + k];
                else if (k >= 20 && k < 120) w = Whh0[row * 100 + (k - 20)];
            } else {
                if (k < 100) w = WihL[(l - 1) * 40000 + row * 100 + k];
                else w = WhhL[(l - 1) * 40000 + row * 100 + (k - 100)];
            }
            tmp[c] = w;
        }
    }
    wbuf[gid] = make_float4(tmp[0], tmp[1], tmp[2], tmp[3]);
}

// 8 packed FMAs (one k-quad, all 4 gates) against register weights w[40].
#define STEP_Q(Q, XQ, A0, A1, A2, A3) { float4 xq_ = (XQ); \
    float2v xlo = (float2v){xq_.x, xq_.y}; \
    float2v xhi = (float2v){xq_.z, xq_.w}; \
    A0 = __builtin_elementwise_fma(w[2*(Q)],      xlo, A0); \
    A0 = __builtin_elementwise_fma(w[2*(Q)+1],    xhi, A0); \
    A1 = __builtin_elementwise_fma(w[10+2*(Q)],   xlo, A1); \
    A1 = __builtin_elementwise_fma(w[10+2*(Q)+1], xhi, A1); \
    A2 = __builtin_elementwise_fma(w[20+2*(Q)],   xlo, A2); \
    A2 = __builtin_elementwise_fma(w[20+2*(Q)+1], xhi, A2); \
    A3 = __builtin_elementwise_fma(w[30+2*(Q)],   xlo, A3); \
    A3 = __builtin_elementwise_fma(w[30+2*(Q)+1], xhi, A3); }

// ---------------- main kernel ----------------
// Split-MAC pipeline, single part4, accumulator-persistent x-partials:
//   I1: x-threads store x-partial(t) (computed last I2); lander lands x(t+1),
//       issues x(t+2); h-threads h-MAC(t) from h(t-1) + store.   [bar lgkm]
//   I2: combine(t) on tid 900..999  ||  x-threads x-MAC(t+1) from xbuf.  [bar lgkm]
// xh float layout: [xbuf 0..99 | h 100..199 | zero-pad 200..223]
template <bool FIRST, bool STORE>
__device__ void run_layer(const float4* __restrict__ wl, const float* __restrict__ bL,
                          const float* __restrict__ xsrc, float* __restrict__ hdst,
                          int b, int tid, int f, int rg,
                          float* xh, float4* part4) {
    // weights -> registers (branch-free, constant dest indices)
    float2v w[40];
#pragma unroll
    for (int g = 0; g < 4; ++g) {
#pragma unroll
        for (int q = 0; q < 5; ++q) {
            float4 t4 = wl[(g * 5 + q) * 1024 + tid];
            w[g * 10 + 2 * q]     = (float2v){t4.x, t4.y};
            w[g * 10 + 2 * q + 1] = (float2v){t4.z, t4.w};
        }
    }
    bool comb = (tid >= 900 && tid < 1000);
    int cu = tid - 900;
    float bi = 0.f, bf = 0.f, bg = 0.f, bo = 0.f;
    if (comb) { bi = bL[cu]; bf = bL[100 + cu]; bg = bL[200 + cu]; bo = bL[300 + cu]; }

    bool xgrp  = FIRST ? (f == 0) : (f < 5);
    bool zchnk = FIRST ? (f >= 6) : (f >= 10);   // zero-weight chunks + dummies
    // MAC read base (float4 units): xbuf @0, h @25, zero-pad @50
    int rb;
    if (FIRST) rb = (f == 0) ? 0 : ((f < 6) ? (25 + 5 * (f - 1)) : 50);
    else       rb = (f < 5) ? (5 * f) : ((f < 10) ? (25 + 5 * (f - 5)) : 50);
    const float4* xv4 = (const float4*)xh + rb;

    // zero xh (all 224 floats) + part4 (zero-chunk slots stay zero all layer)
    if (tid < 56) ((float4*)xh)[tid] = make_float4(0.f, 0.f, 0.f, 0.f);
    for (int i = tid; i < 1000; i += NT) part4[i] = make_float4(0.f, 0.f, 0.f, 0.f);
    __syncthreads();
    // stage x(0) -> xbuf
    if (FIRST) {
        if (tid < 5) xh[tid] = xsrc[(size_t)b * TSEQ * 5 + tid];
    } else {
        if (tid < 25) ((float4*)xh)[tid] = ((const float4*)xsrc)[(size_t)b * TSEQ * 25 + tid];
    }
    __syncthreads();   // full drain: prev-layer hseq stores + x(0) visible

    // prologue: x-partial(0) into persistent accumulators
    float2v xa0 = {0.f, 0.f}, xa1 = {0.f, 0.f}, xa2 = {0.f, 0.f}, xa3 = {0.f, 0.f};
    if (xgrp) {
#pragma unroll
        for (int q = 0; q < 5; ++q) STEP_Q(q, xv4[q], xa0, xa1, xa2, xa3);
    }
    // lander: load x(1) into registers
    bool lx = FIRST ? (tid >= 128 && tid < 133) : (tid >= 128 && tid < 153);
    int li = tid - 128;
    float pfs = 0.f;
    float4 pf4 = {0.f, 0.f, 0.f, 0.f};
    if (lx) {
        if (FIRST) pfs = xsrc[((size_t)b * TSEQ + 1) * 5 + li];
        else pf4 = ((const float4*)xsrc)[((size_t)b * TSEQ + 1) * 25 + li];
    }

    float c = 0.f;
    float* hp = hdst + (size_t)b * TSEQ * 100 + cu;   // combine store pointer

    for (int t = 0; t < TSEQ; ++t) {
        // ---- I1: land x(t+1); issue x(t+2); store x-partial(t); h-MAC(t) ----
        if (lx) {
            if (FIRST) xh[li] = pfs;
            else ((float4*)xh)[li] = pf4;
            int tn = (t + 2 < TSEQ) ? (t + 2) : (TSEQ - 1);
            if (FIRST) pfs = xsrc[((size_t)b * TSEQ + tn) * 5 + li];
            else pf4 = ((const float4*)xsrc)[((size_t)b * TSEQ + tn) * 25 + li];
        }
        if (xgrp) {
            part4[f * 100 + rg] = make_float4(xa0.x + xa0.y, xa1.x + xa1.y,
                                              xa2.x + xa2.y, xa3.x + xa3.y);
        } else if (!zchnk) {
            float2v a0 = {0.f, 0.f}, a1 = {0.f, 0.f}, a2 = {0.f, 0.f}, a3 = {0.f, 0.f};
#pragma unroll
            for (int q = 0; q < 5; ++q) STEP_Q(q, xv4[q], a0, a1, a2, a3);
            part4[f * 100 + rg] = make_float4(a0.x + a0.y, a1.x + a1.y,
                                              a2.x + a2.y, a3.x + a3.y);
        }
        wg_barrier();   // bar1: part4(t) + landed x(t+1) visible

        // ---- I2: combine(t)  ||  x-MAC(t+1) ----
        if (xgrp) {
            xa0 = (float2v){0.f, 0.f}; xa1 = (float2v){0.f, 0.f};
            xa2 = (float2v){0.f, 0.f}; xa3 = (float2v){0.f, 0.f};
#pragma unroll
            for (int q = 0; q < 5; ++q) STEP_Q(q, xv4[q], xa0, xa1, xa2, xa3);
        } else if (comb) {
            float4 p0 = part4[cu];
            float2v sA = (float2v){p0.x, p0.y};
            float2v sB = (float2v){p0.z, p0.w};
#pragma unroll
            for (int ff = 1; ff < 10; ++ff) {
                float4 pp = part4[ff * 100 + cu];
                sA += (float2v){pp.x, pp.y};
                sB += (float2v){pp.z, pp.w};
            }
            float gi = sigmoid_(sA.x + bi);
            float gf = sigmoid_(sA.y + bf);
            float gg = tanh_(sB.x + bg);
            float go = sigmoid_(sB.y + bo);
            c = gf * c + gi * gg;
            float hv = go * tanh_(c);
            xh[100 + cu] = hv;
            if (STORE) { *hp = hv; }   // fire-and-forget
        }
        if (comb) hp += 100;
        wg_barrier();   // bar2: h(t) visible for I1(t+1)
    }
}

#undef STEP_Q

extern "C" __global__ void __launch_bounds__(NT, 4)
gesture_lstm_kernel(const float* __restrict__ x,
                    const float4* __restrict__ wbuf,
                    const float* __restrict__ b0, const float* __restrict__ bLv,
                    const float* __restrict__ gamma, const float* __restrict__ beta,
                    const float* __restrict__ rmean, const float* __restrict__ rvar,
                    const float* __restrict__ W1, const float* __restrict__ b1,
                    const float* __restrict__ W2, const float* __restrict__ b2,
                    const float* __restrict__ W3, const float* __restrict__ b3,
                    float* __restrict__ out, float* __restrict__ hseq) {
    __shared__ __align__(16) float xh[224];
    __shared__ __align__(16) float4 part4[1000];
    __shared__ __align__(16) float hw[10000];

    int tid = threadIdx.x;
    int b = blockIdx.x;
    int f = tid / 100;   // 10 for dummies -> zero-chunk, skipped
    int rg = tid % 100;

    run_layer<true,  true >(wbuf + 0 * 20480, b0,         x,    hseq, b, tid, f, rg, xh, part4);
    run_layer<false, true >(wbuf + 1 * 20480, bLv + 0,    hseq, hseq, b, tid, f, rg, xh, part4);
    run_layer<false, true >(wbuf + 2 * 20480, bLv + 400,  hseq, hseq, b, tid, f, rg, xh, part4);
    run_layer<false, true >(wbuf + 3 * 20480, bLv + 800,  hseq, hseq, b, tid, f, rg, xh, part4);
    run_layer<false, false>(wbuf + 4 * 20480, bLv + 1200, hseq, hseq, b, tid, f, rg, xh, part4);

    // ---- head: BN (inference) -> FC1+ReLU -> FC2+ReLU -> FC3 ----
    float* fcbuf = (float*)part4;
    if (tid < 100) {
        float hv = xh[100 + tid];   // final h lives in the h region
        xh[tid] = (hv - rmean[tid]) * rsqrtf(rvar[tid] + 1e-5f) * gamma[tid] + beta[tid];
    }
    __syncthreads();

    for (int i = tid; i < 2500; i += NT) ((float4*)hw)[i] = ((const float4*)W1)[i];
    __syncthreads();
    if (tid < 100) {
        float acc = b1[tid];
#pragma unroll
        for (int k = 0; k < 100; ++k) acc = fmaf(hw[tid * 100 + k], xh[k], acc);
        fcbuf[tid] = fmaxf(acc, 0.0f);
    }
    __syncthreads();

    for (int i = tid; i < 2500; i += NT) ((float4*)hw)[i] = ((const float4*)W2)[i];
    __syncthreads();
    if (tid < 100) {
        float acc = b2[tid];
#pragma unroll
        for (int k = 0; k < 100; ++k) acc = fmaf(hw[tid * 100 + k], fcbuf[k], acc);
        fcbuf[400 + tid] = fmaxf(acc, 0.0f);
    }
    __syncthreads();

    if (tid < 3) {
        float acc = b3[tid];
#pragma unroll
        for (int k = 0; k < 100; ++k) acc = fmaf(W3[tid * 100 + k], fcbuf[400 + k], acc);
        out[b * 3 + tid] = acc;
    }
}

extern "C" void kernel_launch(void* const* d_in, const int* in_sizes, int n_in,
                              void* d_out, int out_size, void* d_ws, size_t ws_size,
                              hipStream_t stream) {
    const float* x     = (const float*)d_in[0];
    const float* Wih0  = (const float*)d_in[1];
    const float* Whh0  = (const float*)d_in[2];
    const float* b0    = (const float*)d_in[3];
    const float* WihL  = (const float*)d_in[4];
    const float* WhhL  = (const float*)d_in[5];
    const float* bLv   = (const float*)d_in[6];
    const float* gamma = (const float*)d_in[7];
    const float* beta  = (const float*)d_in[8];
    const float* rmean = (const float*)d_in[9];
    const float* rvar  = (const float*)d_in[10];
    const float* W1    = (const float*)d_in[11];
    const float* b1    = (const float*)d_in[12];
    const float* W2    = (const float*)d_in[13];
    const float* b2    = (const float*)d_in[14];
    const float* W3    = (const float*)d_in[15];
    const float* b3    = (const float*)d_in[16];

    float4* wbuf = (float4*)d_ws;                       // 102400 float4 = 1.6375 MB
    float* hseq  = (float*)((char*)d_ws + 102400 * 16); // 256*512*100 fp32 = 52.4 MB

    prep_weights<<<dim3(400), dim3(256), 0, stream>>>(Wih0, Whh0, WihL, WhhL, wbuf);
    gesture_lstm_kernel<<<dim3(256), dim3(NT), 0, stream>>>(
        x, wbuf, b0, bLv, gamma, beta, rmean, rvar, W1, b1, W2, b2, W3, b3,
        (float*)d_out, hseq);
}